// Round 11
// baseline (259.634 us; speedup 1.0000x reference)
//
#include <hip/hip_runtime.h>
#include <hip/hip_bf16.h>

#define GRID_RES 32
#define GRID_DIM 8
#define N_CELLS  256
#define EMB_VOL  512
#define TAB_N    (GRID_RES * GRID_RES * GRID_RES)   // 32768
#define NPT      4
#define BLOCK    1024

// Sparse trilinear interp + analytic gradient. Exact fp32, branchless.
// R5 body (8 scalar gathers/pt, LDS int16 table, float4 I/O) with BLOCK=1024
// + launch_bounds(1024,8) so 2 WGs/CU share the 64KB table: 32 waves/CU for
// latency hiding. Stores stay float4 (R8's float2 stores caused write-allocate
// blowup; float4 kept WRITE at compulsory 39MB in R5/R10).
__global__ __launch_bounds__(BLOCK, 8) void neural_poisson_interp(
    const float* __restrict__ positions,   // [N,3]
    const float* __restrict__ embeddings,  // [NUM_EMB, 512]
    const int*   __restrict__ block_table, // [32,32,32]
    float* __restrict__ out,               // emb[N] | grad[N,3] | mask[N]
    int n)
{
    __shared__ short stab[TAB_N];          // 64 KB, int16 block ids
    {
        const int4* t4 = reinterpret_cast<const int4*>(block_table);
        for (int k = threadIdx.x; k < TAB_N / 4; k += BLOCK) {
            int4 v = t4[k];
            short4 s;
            s.x = (short)v.x; s.y = (short)v.y; s.z = (short)v.z; s.w = (short)v.w;
            *reinterpret_cast<short4*>(&stab[4 * k]) = s;
        }
    }
    __syncthreads();

    float* out_emb  = out;
    float* out_grad = out + (size_t)n;
    float* out_mask = out + 4 * (size_t)n;

    int nq = (n + NPT - 1) / NPT;
    int stride = gridDim.x * BLOCK;
    for (int q = blockIdx.x * BLOCK + threadIdx.x; q < nq; q += stride) {
        int i0 = q * NPT;
        bool full = (i0 + NPT <= n);

        float px[NPT], py[NPT], pz[NPT];
        if (full) {
            const float4* p4 = reinterpret_cast<const float4*>(positions + 3 * (size_t)i0);
            float4 A = p4[0], B = p4[1], C = p4[2];
            px[0]=A.x; py[0]=A.y; pz[0]=A.z;
            px[1]=A.w; py[1]=B.x; pz[1]=B.y;
            px[2]=B.z; py[2]=B.w; pz[2]=C.x;
            px[3]=C.y; py[3]=C.z; pz[3]=C.w;
        } else {
#pragma unroll
            for (int p = 0; p < NPT; ++p) {
                int ip = min(i0 + p, n - 1);
                px[p] = positions[3 * ip + 0];
                py[p] = positions[3 * ip + 1];
                pz[p] = positions[3 * ip + 2];
            }
        }

        float wA[NPT][3], wB[NPT][3];
        int bidx[NPT][8];
        int li  [NPT][8];

#pragma unroll
        for (int p = 0; p < NPT; ++p) {
            float xc[3];
            xc[0] = (px[p] + 1.0f) * 0.5f * (float)(N_CELLS - 1);
            xc[1] = (py[p] + 1.0f) * 0.5f * (float)(N_CELLS - 1);
            xc[2] = (pz[p] + 1.0f) * 0.5f * (float)(N_CELLS - 1);
            int base[3];
#pragma unroll
            for (int a = 0; a < 3; ++a) {
                float bf = fminf(fmaxf(floorf(xc[a]), 0.0f), (float)(N_CELLS - 2));
                float fr = xc[a] - bf;
                wA[p][a] = 1.0f - fr;
                wB[p][a] = fr;
                base[a] = (int)bf;
            }
#pragma unroll
            for (int c = 0; c < 8; ++c) {
                int dx = (c >> 2) & 1, dy = (c >> 1) & 1, dz = c & 1;
                int cx = base[0] + dx, cy = base[1] + dy, cz = base[2] + dz;
                bidx[p][c] = stab[((cx >> 3) * GRID_RES + (cy >> 3)) * GRID_RES
                                  + (cz >> 3)];
                li[p][c] = ((cx & 7) * GRID_DIM + (cy & 7)) * GRID_DIM + (cz & 7);
            }
        }

        // all 32 embedding gathers, branchless (clamped index)
        float e[NPT][8];
#pragma unroll
        for (int p = 0; p < NPT; ++p)
#pragma unroll
            for (int c = 0; c < 8; ++c) {
                int b = bidx[p][c] > 0 ? bidx[p][c] : 0;
                e[p][c] = embeddings[b * EMB_VOL + li[p][c]];
            }

        const float scale = 0.5f * (float)(N_CELLS - 1);  // 127.5
        float acc[NPT], gxv[NPT], gyv[NPT], gzv[NPT], mk[NPT];

#pragma unroll
        for (int p = 0; p < NPT; ++p) {
            float a = 0.0f, gx = 0.0f, gy = 0.0f, gz = 0.0f;
            bool vall = true;
#pragma unroll
            for (int c = 0; c < 8; ++c) {
                int dx = (c >> 2) & 1, dy = (c >> 1) & 1, dz = c & 1;
                bool valid = bidx[p][c] >= 0;
                vall = vall && valid;
                float ev = valid ? e[p][c] : 0.0f;
                float wx = dx ? wB[p][0] : wA[p][0];
                float wy = dy ? wB[p][1] : wA[p][1];
                float wz = dz ? wB[p][2] : wA[p][2];
                a += wx * wy * wz * ev;
                float tgx = wy * wz * ev;
                float tgy = wx * wz * ev;
                float tgz = wx * wy * ev;
                gx += dx ? tgx : -tgx;
                gy += dy ? tgy : -tgy;
                gz += dz ? tgz : -tgz;
            }
            acc[p] = a;
            gxv[p] = scale * gx;
            gyv[p] = scale * gy;
            gzv[p] = scale * gz;
            mk[p]  = vall ? 1.0f : 0.0f;
        }

        if (full) {
            *reinterpret_cast<float4*>(out_emb + i0) =
                make_float4(acc[0], acc[1], acc[2], acc[3]);
            float4* g4 = reinterpret_cast<float4*>(out_grad + 3 * (size_t)i0);
            g4[0] = make_float4(gxv[0], gyv[0], gzv[0], gxv[1]);
            g4[1] = make_float4(gyv[1], gzv[1], gxv[2], gyv[2]);
            g4[2] = make_float4(gzv[2], gxv[3], gyv[3], gzv[3]);
            *reinterpret_cast<float4*>(out_mask + i0) =
                make_float4(mk[0], mk[1], mk[2], mk[3]);
        } else {
#pragma unroll
            for (int p = 0; p < NPT; ++p) {
                int ip = i0 + p;
                if (ip < n) {
                    out_emb[ip]          = acc[p];
                    out_grad[3 * ip + 0] = gxv[p];
                    out_grad[3 * ip + 1] = gyv[p];
                    out_grad[3 * ip + 2] = gzv[p];
                    out_mask[ip]         = mk[p];
                }
            }
        }
    }
}

extern "C" void kernel_launch(void* const* d_in, const int* in_sizes, int n_in,
                              void* d_out, int out_size, void* d_ws, size_t ws_size,
                              hipStream_t stream) {
    const float* positions   = (const float*)d_in[0];
    const float* embeddings  = (const float*)d_in[1];
    const int*   block_table = (const int*)d_in[2];

    int n = in_sizes[0] / 3;
    int nq = (n + NPT - 1) / NPT;

    float* out = (float*)d_out;

    int grid = 512;                           // target 2 WGs/CU
    int maxg = (nq + BLOCK - 1) / BLOCK;
    if (grid > maxg) grid = maxg;
    neural_poisson_interp<<<grid, BLOCK, 0, stream>>>(
        positions, embeddings, block_table, out, n);
}

// Round 12
// 127.876 us; speedup vs baseline: 2.0304x; 2.0304x over previous
//
#include <hip/hip_runtime.h>
#include <hip/hip_bf16.h>

#define GRID_RES 32
#define GRID_DIM 8
#define N_CELLS  256
#define EMB_VOL  512
#define TAB_N    (GRID_RES * GRID_RES * GRID_RES)   // 32768
#define NPT      4
#define BLOCK    1024

// Sparse trilinear interp + analytic gradient. Exact fp32, branchless.
// R5 body, register-packed (bidx+li in 16-bit halves, frac-only weights) to
// fit <=64 VGPR naturally, BLOCK=1024 so 2 WGs/CU share 128KB LDS -> 32
// waves/CU. NO min-waves launch_bounds arg (it forced 32 VGPR + spill in
// R8/R11). Stores float4 (keeps WRITE at compulsory 39MB).
__global__ __launch_bounds__(BLOCK) void neural_poisson_interp(
    const float* __restrict__ positions,   // [N,3]
    const float* __restrict__ embeddings,  // [NUM_EMB, 512]
    const int*   __restrict__ block_table, // [32,32,32]
    float* __restrict__ out,               // emb[N] | grad[N,3] | mask[N]
    int n)
{
    __shared__ short stab[TAB_N];          // 64 KB, int16 block ids
    {
        const int4* t4 = reinterpret_cast<const int4*>(block_table);
        for (int k = threadIdx.x; k < TAB_N / 4; k += BLOCK) {
            int4 v = t4[k];
            short4 s;
            s.x = (short)v.x; s.y = (short)v.y; s.z = (short)v.z; s.w = (short)v.w;
            *reinterpret_cast<short4*>(&stab[4 * k]) = s;
        }
    }
    __syncthreads();

    float* out_emb  = out;
    float* out_grad = out + (size_t)n;
    float* out_mask = out + 4 * (size_t)n;

    int nq = (n + NPT - 1) / NPT;
    int stride = gridDim.x * BLOCK;
    for (int q = blockIdx.x * BLOCK + threadIdx.x; q < nq; q += stride) {
        int i0 = q * NPT;
        bool full = (i0 + NPT <= n);

        float px[NPT], py[NPT], pz[NPT];
        if (full) {
            const float4* p4 = reinterpret_cast<const float4*>(positions + 3 * (size_t)i0);
            float4 A = p4[0], B = p4[1], C = p4[2];
            px[0]=A.x; py[0]=A.y; pz[0]=A.z;
            px[1]=A.w; py[1]=B.x; pz[1]=B.y;
            px[2]=B.z; py[2]=B.w; pz[2]=C.x;
            px[3]=C.y; py[3]=C.z; pz[3]=C.w;
        } else {
#pragma unroll
            for (int p = 0; p < NPT; ++p) {
                int ip = min(i0 + p, n - 1);
                px[p] = positions[3 * ip + 0];
                py[p] = positions[3 * ip + 1];
                pz[p] = positions[3 * ip + 2];
            }
        }

        float fr[NPT][3];      // frac only; weights recomputed in compute phase
        int bpk[NPT][4];       // corner block ids, 2x int16 per int
        int lpk[NPT][4];       // corner local offsets (0..511), 2x per int

#pragma unroll
        for (int p = 0; p < NPT; ++p) {
            float xc[3];
            xc[0] = (px[p] + 1.0f) * 0.5f * (float)(N_CELLS - 1);
            xc[1] = (py[p] + 1.0f) * 0.5f * (float)(N_CELLS - 1);
            xc[2] = (pz[p] + 1.0f) * 0.5f * (float)(N_CELLS - 1);
            int base[3];
#pragma unroll
            for (int a = 0; a < 3; ++a) {
                float bf = fminf(fmaxf(floorf(xc[a]), 0.0f), (float)(N_CELLS - 2));
                fr[p][a] = xc[a] - bf;
                base[a] = (int)bf;
            }
#pragma unroll
            for (int k = 0; k < 4; ++k) {       // corner pair (2k, 2k+1)
                int c0 = 2 * k, c1 = 2 * k + 1;
                int dx0 = (c0 >> 2) & 1, dy0 = (c0 >> 1) & 1, dz0 = c0 & 1;
                int dx1 = (c1 >> 2) & 1, dy1 = (c1 >> 1) & 1, dz1 = c1 & 1;
                int cx0 = base[0] + dx0, cy0 = base[1] + dy0, cz0 = base[2] + dz0;
                int cx1 = base[0] + dx1, cy1 = base[1] + dy1, cz1 = base[2] + dz1;
                int t0 = stab[((cx0 >> 3) * GRID_RES + (cy0 >> 3)) * GRID_RES + (cz0 >> 3)];
                int t1 = stab[((cx1 >> 3) * GRID_RES + (cy1 >> 3)) * GRID_RES + (cz1 >> 3)];
                bpk[p][k] = (t0 & 0xffff) | (t1 << 16);
                int l0 = ((cx0 & 7) * GRID_DIM + (cy0 & 7)) * GRID_DIM + (cz0 & 7);
                int l1 = ((cx1 & 7) * GRID_DIM + (cy1 & 7)) * GRID_DIM + (cz1 & 7);
                lpk[p][k] = l0 | (l1 << 16);
            }
        }

        // all 32 embedding gathers, branchless (clamped index)
        float e[NPT][8];
#pragma unroll
        for (int p = 0; p < NPT; ++p)
#pragma unroll
            for (int c = 0; c < 8; ++c) {
                int v = bpk[p][c >> 1];
                int t = (c & 1) ? (v >> 16) : (int)(short)(v & 0xffff);
                int lv = lpk[p][c >> 1];
                int li = (c & 1) ? (lv >> 16) : (lv & 0xffff);
                int b = t > 0 ? t : 0;
                e[p][c] = embeddings[b * EMB_VOL + li];
            }

        const float scale = 0.5f * (float)(N_CELLS - 1);  // 127.5
        float acc[NPT], gxv[NPT], gyv[NPT], gzv[NPT], mk[NPT];

#pragma unroll
        for (int p = 0; p < NPT; ++p) {
            float fx = fr[p][0], fy = fr[p][1], fz = fr[p][2];
            float ox = 1.0f - fx, oy = 1.0f - fy, oz = 1.0f - fz;
            float a = 0.0f, gx = 0.0f, gy = 0.0f, gz = 0.0f;
            int sgn = -1;
#pragma unroll
            for (int c = 0; c < 8; ++c) {
                int dx = (c >> 2) & 1, dy = (c >> 1) & 1, dz = c & 1;
                int v = bpk[p][c >> 1];
                int t = (c & 1) ? (v >> 16) : (int)(short)(v & 0xffff);
                sgn &= t;
                float ev = t >= 0 ? e[p][c] : 0.0f;
                float wx = dx ? fx : ox;
                float wy = dy ? fy : oy;
                float wz = dz ? fz : oz;
                a += wx * wy * wz * ev;
                float tgx = wy * wz * ev;
                float tgy = wx * wz * ev;
                float tgz = wx * wy * ev;
                gx += dx ? tgx : -tgx;
                gy += dy ? tgy : -tgy;
                gz += dz ? tgz : -tgz;
            }
            acc[p] = a;
            gxv[p] = scale * gx;
            gyv[p] = scale * gy;
            gzv[p] = scale * gz;
            mk[p]  = (sgn >= 0) ? 1.0f : 0.0f;
        }

        if (full) {
            *reinterpret_cast<float4*>(out_emb + i0) =
                make_float4(acc[0], acc[1], acc[2], acc[3]);
            float4* g4 = reinterpret_cast<float4*>(out_grad + 3 * (size_t)i0);
            g4[0] = make_float4(gxv[0], gyv[0], gzv[0], gxv[1]);
            g4[1] = make_float4(gyv[1], gzv[1], gxv[2], gyv[2]);
            g4[2] = make_float4(gzv[2], gxv[3], gyv[3], gzv[3]);
            *reinterpret_cast<float4*>(out_mask + i0) =
                make_float4(mk[0], mk[1], mk[2], mk[3]);
        } else {
#pragma unroll
            for (int p = 0; p < NPT; ++p) {
                int ip = i0 + p;
                if (ip < n) {
                    out_emb[ip]          = acc[p];
                    out_grad[3 * ip + 0] = gxv[p];
                    out_grad[3 * ip + 1] = gyv[p];
                    out_grad[3 * ip + 2] = gzv[p];
                    out_mask[ip]         = mk[p];
                }
            }
        }
    }
}

extern "C" void kernel_launch(void* const* d_in, const int* in_sizes, int n_in,
                              void* d_out, int out_size, void* d_ws, size_t ws_size,
                              hipStream_t stream) {
    const float* positions   = (const float*)d_in[0];
    const float* embeddings  = (const float*)d_in[1];
    const int*   block_table = (const int*)d_in[2];

    int n = in_sizes[0] / 3;
    int nq = (n + NPT - 1) / NPT;

    float* out = (float*)d_out;

    int grid = 512;                           // target 2 WGs/CU (32 waves/CU)
    int maxg = (nq + BLOCK - 1) / BLOCK;
    if (grid > maxg) grid = maxg;
    neural_poisson_interp<<<grid, BLOCK, 0, stream>>>(
        positions, embeddings, block_table, out, n);
}